// Round 5
// baseline (175.115 us; speedup 1.0000x reference)
//
#include <hip/hip_runtime.h>
#include <hip/hip_bf16.h>
#include <math.h>

#define N_SAMPLES 262144
#define DDIM 64
#define KDIM 64
#define NBLOCKS 2048          // 2048 blocks x 4 waves x 2 tiles x 16 rows
#define TPW 2                 // tiles per wave
#define NPART (NBLOCKS * 4)   // one partial per wave

#define LOG2PI 1.8378770664093453f
#define PRIOR_LV0 -2.0f
#define IV0 7.389056098930650f  /* exp(2.0) */

// ws layout (floats):
//   [0, 4096)        : Bsw — 16 KB bf16 MFMA coef fragments
//                      frag-set s = kc*4+tile; lane l: 8 bf16 =
//                      B[kc*32 + (l>>4)*8 + j][tile*16 + (l&15)], j=0..7
//                      B[r][k] = r<64 ? P'[k][d=r] : Q[k][d=r-64]
//                      (same bits serve as the A-operand of the swapped
//                       mfma: A[m=cluster][k=d] fragment)
//   [4096, 4160)     : c[k]            (lp bias)
//   [4160, 4224)     : c[k] + logpi[k] (LSE bias, fused)
//   [4224, 4224+NPART): per-wave LSE partials (plain stores)
//   [WS_KL]          : kl_phi * N  (written by setup)

#define WS_C      4096
#define WS_CL     4160
#define WS_PART   4224
#define WS_KL     (WS_PART + NPART)

typedef __attribute__((ext_vector_type(8))) short short8;
typedef __attribute__((ext_vector_type(4))) float floatx4;

static __device__ inline unsigned short f2bf_bits(float f) {
  union { float f; unsigned u; } v; v.f = f;
  unsigned r = v.u + 0x7fffu + ((v.u >> 16) & 1u);  // RNE
  return (unsigned short)(r >> 16);
}

__global__ __launch_bounds__(256) void setup_frags(
    const float* __restrict__ u_noise, const float* __restrict__ phi_logits,
    const float* __restrict__ q_mu, const float* __restrict__ q_logvar,
    const float* __restrict__ pi_logits, const float* __restrict__ prior_p,
    float* __restrict__ out, float* __restrict__ ws) {
  __shared__ float sPhi[DDIM];
  __shared__ float sR[DDIM];
  __shared__ float sLpi[KDIM];
  __shared__ float sBeta;
  __shared__ float sPart[4][KDIM];
  int tid = threadIdx.x;

  if (tid < 64) {  // exactly wave 0
    int d = tid;
    float u = u_noise[d];
    float g = -__logf(-__logf(u + 1e-9f) + 1e-9f);
    float phi = 1.0f / (1.0f + __expf(-(phi_logits[d] + g)));  // TEMP=1
    sPhi[d] = phi;
    sR[d] = -0.5f * (1.0f - phi) * IV0;

    float betap = -0.5f * (1.0f - phi) * (LOG2PI + PRIOR_LV0);
    #pragma unroll
    for (int o = 1; o < 64; o <<= 1) betap += __shfl_xor(betap, o, 64);
    if (d == 0) sBeta = betap;

    // log(softmax(pi_logits) + 1e-9)
    float l = pi_logits[d];
    float m = l;
    #pragma unroll
    for (int o = 1; o < 64; o <<= 1) m = fmaxf(m, __shfl_xor(m, o, 64));
    float e = __expf(l - m);
    float s = e;
    #pragma unroll
    for (int o = 1; o < 64; o <<= 1) s += __shfl_xor(s, o, 64);
    sLpi[d] = __logf(e / s + 1e-9f);
  } else if (tid >= 64 && tid < 128) {  // wave 1: q_phi + kl_phi
    int d = tid - 64;
    float qp = 1.0f / (1.0f + __expf(-phi_logits[d]));
    qp = fminf(fmaxf(qp, 1e-6f), 1.0f - 1e-6f);
    out[1 + d] = qp;
    float pp = fminf(fmaxf(prior_p[d], 1e-6f), 1.0f - 1e-6f);
    float klp = qp * (__logf(qp) - __logf(pp)) +
                (1.0f - qp) * (__logf(1.0f - qp) - __logf(1.0f - pp));
    #pragma unroll
    for (int o = 1; o < 64; o <<= 1) klp += __shfl_xor(klp, o, 64);
    if (d == 0) ws[WS_KL] = klp * (float)N_SAMPLES;
  }
  __syncthreads();

  // c_k partials (256 threads: k = tid&63, d-segment = tid>>6)
  {
    int k = tid & 63, seg = tid >> 6;
    const float* lvp = q_logvar + k * DDIM + seg * 16;
    const float* mup = q_mu + k * DDIM + seg * 16;
    float ap = 0.0f;
    #pragma unroll
    for (int dd = 0; dd < 16; ++dd) {
      int d = seg * 16 + dd;
      float lv = fminf(fmaxf(lvp[dd], -5.0f), 5.0f);
      float mu = mup[dd];
      ap += sPhi[d] * (LOG2PI + lv) + mu * mu * sPhi[d] * __expf(-lv);
    }
    sPart[seg][k] = ap;
  }

  // B-fragments built directly from params
  unsigned short* bsw = (unsigned short*)ws;
  #pragma unroll
  for (int p = 0; p < 4; ++p) {
    int pr = p * 256 + tid;      // 0..1023 = frag-set*64 + lane
    int s = pr >> 6, l = pr & 63;
    int kc = s >> 2, tl = s & 3, q = l >> 4, nn = l & 15;
    int k = tl * 16 + nn;
    int dbase = (kc & 1) * 32 + q * 8;
    const float* lvp = q_logvar + k * DDIM + dbase;
    float4 lv0 = *(const float4*)lvp;
    float4 lv1 = *(const float4*)(lvp + 4);
    float lvv[8] = {lv0.x, lv0.y, lv0.z, lv0.w, lv1.x, lv1.y, lv1.z, lv1.w};
    short r8[8];
    if (kc < 2) {  // P' rows
      #pragma unroll
      for (int j = 0; j < 8; ++j) {
        int d = dbase + j;
        float lv = fminf(fmaxf(lvv[j], -5.0f), 5.0f);
        r8[j] = (short)f2bf_bits(-0.5f * sPhi[d] * __expf(-lv) + sR[d]);
      }
    } else {       // Q rows
      const float* mup = q_mu + k * DDIM + dbase;
      float4 mu0 = *(const float4*)mup;
      float4 mu1 = *(const float4*)(mup + 4);
      float muv[8] = {mu0.x, mu0.y, mu0.z, mu0.w, mu1.x, mu1.y, mu1.z, mu1.w};
      #pragma unroll
      for (int j = 0; j < 8; ++j) {
        int d = dbase + j;
        float lv = fminf(fmaxf(lvv[j], -5.0f), 5.0f);
        r8[j] = (short)f2bf_bits(muv[j] * sPhi[d] * __expf(-lv));
      }
    }
    ((short8*)bsw)[pr] = (short8){r8[0], r8[1], r8[2], r8[3],
                                  r8[4], r8[5], r8[6], r8[7]};
  }

  __syncthreads();
  if (tid < 64) {
    float alpha = sPart[0][tid] + sPart[1][tid] + sPart[2][tid] + sPart[3][tid];
    float c = -0.5f * alpha + sBeta;  // c_k
    ws[WS_C + tid] = c;
    ws[WS_CL + tid] = c + sLpi[tid];  // c_k + log pi_k
  }
}

// Main kernel: 2048 blocks x 4 waves x 2 tiles of 16 rows.
// B coef table + bias tables staged in LDS once per block (R4 win);
// BOTH tiles' X loads issued before the staging barrier (8x16B in
// flight per lane — doubles MLP vs R4 to push HBM toward saturation).
// No atomics; per-wave partial via plain store.
__global__ __launch_bounds__(256, 8) void gmm_main(
    const float* __restrict__ X, float* __restrict__ ws,
    float* __restrict__ out) {
  __shared__ short8 sB[1024];     // 16 KB: 16 frag-sets x 64 lanes
  __shared__ float sCB[KDIM];     // c_k
  __shared__ float sCL[KDIM];     // c_k + log pi_k
  int tid  = threadIdx.x;
  int lane = tid & 63;
  int w    = tid >> 6;
  int n    = lane & 15;   // sample within tile == C/D column
  int q    = lane >> 4;   // quad: C/D rows (clusters) q*4..q*4+3
  long wavebase = ((long)blockIdx.x * 4 + w) * (16 * TPW);

  // ---- X loads for BOTH tiles issued first (8 outstanding 16B loads)
  const float* xr = X + (wavebase + n) * DDIM + q * 8;
  float4 p0a = *(const float4*)(xr);
  float4 p0b = *(const float4*)(xr + 4);
  float4 p0c = *(const float4*)(xr + 32);
  float4 p0d = *(const float4*)(xr + 36);
  const float* xr1 = xr + 16 * DDIM;
  float4 p1a = *(const float4*)(xr1);
  float4 p1b = *(const float4*)(xr1 + 4);
  float4 p1c = *(const float4*)(xr1 + 32);
  float4 p1d = *(const float4*)(xr1 + 36);

  // ---- stage B frags + bias tables into LDS (once per block)
  {
    const short8* Bf = (const short8*)ws;
    #pragma unroll
    for (int p = 0; p < 4; ++p) sB[p * 256 + tid] = Bf[p * 256 + tid];
    if (tid < KDIM) { sCB[tid] = ws[WS_C + tid]; sCL[tid] = ws[WS_CL + tid]; }
  }
  __syncthreads();

  float* lp = out + 1 + DDIM;     // float-offset 65
  float lseacc = 0.0f;

  #pragma unroll
  for (int it = 0; it < TPW; ++it) {
    float xa[8], xb[8];
    if (it == 0) {
      xa[0]=p0a.x; xa[1]=p0a.y; xa[2]=p0a.z; xa[3]=p0a.w;
      xa[4]=p0b.x; xa[5]=p0b.y; xa[6]=p0b.z; xa[7]=p0b.w;
      xb[0]=p0c.x; xb[1]=p0c.y; xb[2]=p0c.z; xb[3]=p0c.w;
      xb[4]=p0d.x; xb[5]=p0d.y; xb[6]=p0d.z; xb[7]=p0d.w;
    } else {
      xa[0]=p1a.x; xa[1]=p1a.y; xa[2]=p1a.z; xa[3]=p1a.w;
      xa[4]=p1b.x; xa[5]=p1b.y; xa[6]=p1b.z; xa[7]=p1b.w;
      xb[0]=p1c.x; xb[1]=p1c.y; xb[2]=p1c.z; xb[3]=p1c.w;
      xb[4]=p1d.x; xb[5]=p1d.y; xb[6]=p1d.z; xb[7]=p1d.w;
    }

    // ---- X fragments: kc0 = x^2 lo, kc1 = x^2 hi, kc2 = x lo, kc3 = x hi
    short8 a[4];
    #pragma unroll
    for (int j = 0; j < 8; ++j) {
      a[0][j] = (short)f2bf_bits(xa[j] * xa[j]);
      a[1][j] = (short)f2bf_bits(xb[j] * xb[j]);
      a[2][j] = (short)f2bf_bits(xa[j]);
      a[3][j] = (short)f2bf_bits(xb[j]);
    }

    // ---- MFMA: coef frags (LDS) as A, X frags as B -> D[cluster][sample]
    floatx4 acc[4];
    #pragma unroll
    for (int t = 0; t < 4; ++t) acc[t] = (floatx4){0.f, 0.f, 0.f, 0.f};
    #pragma unroll
    for (int kc = 0; kc < 4; ++kc) {
      #pragma unroll
      for (int t = 0; t < 4; ++t) {
        short8 b = sB[(kc * 4 + t) * 64 + lane];
        acc[t] = __builtin_amdgcn_mfma_f32_16x16x32_bf16(b, a[kc], acc[t], 0, 0, 0);
      }
    }

    // ---- epilogue: bias + 16B store per tile-col + lane-local LSE
    long rowoff = (wavebase + it * 16 + n) * KDIM;
    #pragma unroll
    for (int t = 0; t < 4; ++t) {
      float4 cb = *(const float4*)&sCB[t * 16 + q * 4];
      float4 cl = *(const float4*)&sCL[t * 16 + q * 4];
      float o4[4];
      o4[0] = acc[t][0] + cb.x;
      o4[1] = acc[t][1] + cb.y;
      o4[2] = acc[t][2] + cb.z;
      o4[3] = acc[t][3] + cb.w;
      // 16B store at 4B alignment (gfx950 unaligned global access)
      __builtin_memcpy(lp + rowoff + t * 16 + q * 4, o4, 16);
      acc[t][0] += cl.x;
      acc[t][1] += cl.y;
      acc[t][2] += cl.z;
      acc[t][3] += cl.w;
    }

    float m = acc[0][0];
    #pragma unroll
    for (int t = 0; t < 4; ++t)
      #pragma unroll
      for (int r = 0; r < 4; ++r) m = fmaxf(m, acc[t][r]);
    m = fmaxf(m, __shfl_xor(m, 16, 64));
    m = fmaxf(m, __shfl_xor(m, 32, 64));

    float s = 0.0f;
    #pragma unroll
    for (int t = 0; t < 4; ++t)
      #pragma unroll
      for (int r = 0; r < 4; ++r) s += __expf(acc[t][r] - m);
    s += __shfl_xor(s, 16, 64);
    s += __shfl_xor(s, 32, 64);

    lseacc += m + __logf(s);  // per-sample; identical across q-groups
  }

  // sum the 16 samples (butterfly; q-groups identical)
  lseacc += __shfl_xor(lseacc, 1, 64);
  lseacc += __shfl_xor(lseacc, 2, 64);
  lseacc += __shfl_xor(lseacc, 4, 64);
  lseacc += __shfl_xor(lseacc, 8, 64);
  if (lane == 0) ws[WS_PART + blockIdx.x * 4 + w] = lseacc;
}

// Final: sum per-wave partials, combine with kl from ws.
__global__ __launch_bounds__(256) void finalize_kernel(
    const float* __restrict__ ws, float* __restrict__ out) {
  __shared__ float sW[4];
  int tid = threadIdx.x;
  int lane = tid & 63, w = tid >> 6;

  float s = 0.0f;
  #pragma unroll
  for (int i = 0; i < NPART / 256; ++i)
    s += ws[WS_PART + i * 256 + tid];
  #pragma unroll
  for (int o = 1; o < 64; o <<= 1) s += __shfl_xor(s, o, 64);
  if (lane == 0) sW[w] = s;
  __syncthreads();
  if (tid == 0) out[0] = ws[WS_KL] - (sW[0] + sW[1] + sW[2] + sW[3]);
}

extern "C" void kernel_launch(void* const* d_in, const int* in_sizes, int n_in,
                              void* d_out, int out_size, void* d_ws, size_t ws_size,
                              hipStream_t stream) {
  const float* X           = (const float*)d_in[0];
  const float* u_noise     = (const float*)d_in[1];
  const float* phi_logits  = (const float*)d_in[2];
  const float* q_mu        = (const float*)d_in[3];
  const float* q_logvar    = (const float*)d_in[4];
  const float* pi_logits   = (const float*)d_in[5];
  const float* prior_p     = (const float*)d_in[6];
  float* out = (float*)d_out;
  float* ws  = (float*)d_ws;

  setup_frags<<<1, 256, 0, stream>>>(u_noise, phi_logits, q_mu, q_logvar,
                                     pi_logits, prior_p, out, ws);
  gmm_main<<<NBLOCKS, 256, 0, stream>>>(X, ws, out);
  finalize_kernel<<<1, 256, 0, stream>>>(ws, out);
}

// Round 6
// 164.683 us; speedup vs baseline: 1.0633x; 1.0633x over previous
//
#include <hip/hip_runtime.h>
#include <hip/hip_bf16.h>
#include <math.h>

#define N_SAMPLES 262144
#define DDIM 64
#define KDIM 64
#define NBLOCKS 4096          // 4096 blocks x 4 waves x 16 rows (frozen grid:
                              // multi-tile waves inflate WRITE 2.3x — R2/R5)
#define NPART (NBLOCKS * 4)   // one partial per wave

#define LOG2PI 1.8378770664093453f
#define PRIOR_LV0 -2.0f
#define IV0 7.389056098930650f  /* exp(2.0) */

// ws layout (floats):
//   [0, 4096)        : Bsw — 16 KB bf16 MFMA coef fragments
//                      frag-set s = kc*4+tile; lane l: 8 bf16 =
//                      B[kc*32 + (l>>4)*8 + j][tile*16 + (l&15)], j=0..7
//                      B[r][k] = r<64 ? P'[k][d=r] : Q[k][d=r-64]
//                      (same bits serve as the A-operand of the swapped
//                       mfma: A[m=cluster][k=d] fragment)
//   [4096, 4160)     : c[k]            (lp bias)
//   [4160, 4224)     : c[k] + logpi[k] (LSE bias, fused)
//   [4224, 4224+NPART): per-wave LSE partials (plain stores)
//   [WS_KL]          : kl_phi * N  (written by setup)

#define WS_C      4096
#define WS_CL     4160
#define WS_PART   4224
#define WS_KL     (WS_PART + NPART)

typedef __attribute__((ext_vector_type(8))) short short8;
typedef __attribute__((ext_vector_type(4))) float floatx4;
typedef floatx4 __attribute__((aligned(4))) floatx4_u;   // 4B-aligned 16B vec

static __device__ inline unsigned short f2bf_bits(float f) {
  union { float f; unsigned u; } v; v.f = f;
  unsigned r = v.u + 0x7fffu + ((v.u >> 16) & 1u);  // RNE
  return (unsigned short)(r >> 16);
}

__global__ __launch_bounds__(256) void setup_frags(
    const float* __restrict__ u_noise, const float* __restrict__ phi_logits,
    const float* __restrict__ q_mu, const float* __restrict__ q_logvar,
    const float* __restrict__ pi_logits, const float* __restrict__ prior_p,
    float* __restrict__ out, float* __restrict__ ws) {
  __shared__ float sPhi[DDIM];
  __shared__ float sR[DDIM];
  __shared__ float sLpi[KDIM];
  __shared__ float sBeta;
  __shared__ float sPart[4][KDIM];
  int tid = threadIdx.x;

  if (tid < 64) {  // exactly wave 0
    int d = tid;
    float u = u_noise[d];
    float g = -__logf(-__logf(u + 1e-9f) + 1e-9f);
    float phi = 1.0f / (1.0f + __expf(-(phi_logits[d] + g)));  // TEMP=1
    sPhi[d] = phi;
    sR[d] = -0.5f * (1.0f - phi) * IV0;

    float betap = -0.5f * (1.0f - phi) * (LOG2PI + PRIOR_LV0);
    #pragma unroll
    for (int o = 1; o < 64; o <<= 1) betap += __shfl_xor(betap, o, 64);
    if (d == 0) sBeta = betap;

    // log(softmax(pi_logits) + 1e-9)
    float l = pi_logits[d];
    float m = l;
    #pragma unroll
    for (int o = 1; o < 64; o <<= 1) m = fmaxf(m, __shfl_xor(m, o, 64));
    float e = __expf(l - m);
    float s = e;
    #pragma unroll
    for (int o = 1; o < 64; o <<= 1) s += __shfl_xor(s, o, 64);
    sLpi[d] = __logf(e / s + 1e-9f);
  } else if (tid >= 64 && tid < 128) {  // wave 1: q_phi + kl_phi
    int d = tid - 64;
    float qp = 1.0f / (1.0f + __expf(-phi_logits[d]));
    qp = fminf(fmaxf(qp, 1e-6f), 1.0f - 1e-6f);
    out[1 + d] = qp;
    float pp = fminf(fmaxf(prior_p[d], 1e-6f), 1.0f - 1e-6f);
    float klp = qp * (__logf(qp) - __logf(pp)) +
                (1.0f - qp) * (__logf(1.0f - qp) - __logf(1.0f - pp));
    #pragma unroll
    for (int o = 1; o < 64; o <<= 1) klp += __shfl_xor(klp, o, 64);
    if (d == 0) ws[WS_KL] = klp * (float)N_SAMPLES;
  }
  __syncthreads();

  // c_k partials (256 threads: k = tid&63, d-segment = tid>>6)
  {
    int k = tid & 63, seg = tid >> 6;
    const float* lvp = q_logvar + k * DDIM + seg * 16;
    const float* mup = q_mu + k * DDIM + seg * 16;
    float ap = 0.0f;
    #pragma unroll
    for (int dd = 0; dd < 16; ++dd) {
      int d = seg * 16 + dd;
      float lv = fminf(fmaxf(lvp[dd], -5.0f), 5.0f);
      float mu = mup[dd];
      ap += sPhi[d] * (LOG2PI + lv) + mu * mu * sPhi[d] * __expf(-lv);
    }
    sPart[seg][k] = ap;
  }

  // B-fragments built directly from params
  unsigned short* bsw = (unsigned short*)ws;
  #pragma unroll
  for (int p = 0; p < 4; ++p) {
    int pr = p * 256 + tid;      // 0..1023 = frag-set*64 + lane
    int s = pr >> 6, l = pr & 63;
    int kc = s >> 2, tl = s & 3, q = l >> 4, nn = l & 15;
    int k = tl * 16 + nn;
    int dbase = (kc & 1) * 32 + q * 8;
    const float* lvp = q_logvar + k * DDIM + dbase;
    float4 lv0 = *(const float4*)lvp;
    float4 lv1 = *(const float4*)(lvp + 4);
    float lvv[8] = {lv0.x, lv0.y, lv0.z, lv0.w, lv1.x, lv1.y, lv1.z, lv1.w};
    short r8[8];
    if (kc < 2) {  // P' rows
      #pragma unroll
      for (int j = 0; j < 8; ++j) {
        int d = dbase + j;
        float lv = fminf(fmaxf(lvv[j], -5.0f), 5.0f);
        r8[j] = (short)f2bf_bits(-0.5f * sPhi[d] * __expf(-lv) + sR[d]);
      }
    } else {       // Q rows
      const float* mup = q_mu + k * DDIM + dbase;
      float4 mu0 = *(const float4*)mup;
      float4 mu1 = *(const float4*)(mup + 4);
      float muv[8] = {mu0.x, mu0.y, mu0.z, mu0.w, mu1.x, mu1.y, mu1.z, mu1.w};
      #pragma unroll
      for (int j = 0; j < 8; ++j) {
        int d = dbase + j;
        float lv = fminf(fmaxf(lvv[j], -5.0f), 5.0f);
        r8[j] = (short)f2bf_bits(muv[j] * sPhi[d] * __expf(-lv));
      }
    }
    ((short8*)bsw)[pr] = (short8){r8[0], r8[1], r8[2], r8[3],
                                  r8[4], r8[5], r8[6], r8[7]};
  }

  __syncthreads();
  if (tid < 64) {
    float alpha = sPart[0][tid] + sPart[1][tid] + sPart[2][tid] + sPart[3][tid];
    float c = -0.5f * alpha + sBeta;  // c_k
    ws[WS_C + tid] = c;
    ws[WS_CL + tid] = c + sLpi[tid];  // c_k + log pi_k
  }
}

// Main kernel: R4 structure frozen (4096 blocks x 4 waves, one 16-row tile
// per wave; B coef table + bias tables staged in LDS once per block).
// R6 delta: non-temporal X loads (read-once) and non-temporal lp stores
// (write-once, never re-read) — keeps the 67 MB of lp lines out of L2 so
// the B-staging reads and X stream keep the cache.
__global__ __launch_bounds__(256, 8) void gmm_main(
    const float* __restrict__ X, float* __restrict__ ws,
    float* __restrict__ out) {
  __shared__ short8 sB[1024];     // 16 KB: 16 frag-sets x 64 lanes
  __shared__ float sCB[KDIM];     // c_k
  __shared__ float sCL[KDIM];     // c_k + log pi_k
  int tid  = threadIdx.x;
  int lane = tid & 63;
  int w    = tid >> 6;
  int n    = lane & 15;   // sample within tile == C/D column
  int q    = lane >> 4;   // quad: C/D rows (clusters) q*4..q*4+3
  long rbase = ((long)blockIdx.x * 4 + w) * 16;

  // ---- X loads issued first (independent of LDS staging; hide HBM latency)
  const float* xr = X + (rbase + n) * DDIM + q * 8;
  floatx4 xa0 = __builtin_nontemporal_load((const floatx4*)(xr));
  floatx4 xa1 = __builtin_nontemporal_load((const floatx4*)(xr + 4));
  floatx4 xb0 = __builtin_nontemporal_load((const floatx4*)(xr + 32));
  floatx4 xb1 = __builtin_nontemporal_load((const floatx4*)(xr + 36));

  // ---- stage B frags + bias tables into LDS (once per block)
  {
    const short8* Bf = (const short8*)ws;
    #pragma unroll
    for (int p = 0; p < 4; ++p) sB[p * 256 + tid] = Bf[p * 256 + tid];
    if (tid < KDIM) { sCB[tid] = ws[WS_C + tid]; sCL[tid] = ws[WS_CL + tid]; }
  }
  __syncthreads();

  // ---- X fragments: kc0 = x^2 lo, kc1 = x^2 hi, kc2 = x lo, kc3 = x hi
  short8 a[4];
  {
    float xa[8] = {xa0[0], xa0[1], xa0[2], xa0[3], xa1[0], xa1[1], xa1[2], xa1[3]};
    float xb[8] = {xb0[0], xb0[1], xb0[2], xb0[3], xb1[0], xb1[1], xb1[2], xb1[3]};
    #pragma unroll
    for (int j = 0; j < 8; ++j) {
      a[0][j] = (short)f2bf_bits(xa[j] * xa[j]);
      a[1][j] = (short)f2bf_bits(xb[j] * xb[j]);
      a[2][j] = (short)f2bf_bits(xa[j]);
      a[3][j] = (short)f2bf_bits(xb[j]);
    }
  }

  // ---- MFMA: coef frags (LDS) as A, X frags as B -> D[cluster][sample]
  floatx4 acc[4];
  #pragma unroll
  for (int t = 0; t < 4; ++t) acc[t] = (floatx4){0.f, 0.f, 0.f, 0.f};
  #pragma unroll
  for (int kc = 0; kc < 4; ++kc) {
    #pragma unroll
    for (int t = 0; t < 4; ++t) {
      short8 b = sB[(kc * 4 + t) * 64 + lane];
      acc[t] = __builtin_amdgcn_mfma_f32_16x16x32_bf16(b, a[kc], acc[t], 0, 0, 0);
    }
  }

  // ---- epilogue: bias + 16B NT store per tile-col + lane-local LSE
  float* lp = out + 1 + DDIM;           // float-offset 65
  long rowoff = (rbase + n) * KDIM;
  #pragma unroll
  for (int t = 0; t < 4; ++t) {
    float4 cb = *(const float4*)&sCB[t * 16 + q * 4];
    float4 cl = *(const float4*)&sCL[t * 16 + q * 4];
    floatx4 o4;
    o4[0] = acc[t][0] + cb.x;
    o4[1] = acc[t][1] + cb.y;
    o4[2] = acc[t][2] + cb.z;
    o4[3] = acc[t][3] + cb.w;
    // 16B NT store at 4B alignment (gfx950 handles unaligned global)
    __builtin_nontemporal_store(o4, (floatx4_u*)(lp + rowoff + t * 16 + q * 4));
    acc[t][0] += cl.x;
    acc[t][1] += cl.y;
    acc[t][2] += cl.z;
    acc[t][3] += cl.w;
  }

  float m = acc[0][0];
  #pragma unroll
  for (int t = 0; t < 4; ++t)
    #pragma unroll
    for (int r = 0; r < 4; ++r) m = fmaxf(m, acc[t][r]);
  m = fmaxf(m, __shfl_xor(m, 16, 64));
  m = fmaxf(m, __shfl_xor(m, 32, 64));

  float s = 0.0f;
  #pragma unroll
  for (int t = 0; t < 4; ++t)
    #pragma unroll
    for (int r = 0; r < 4; ++r) s += __expf(acc[t][r] - m);
  s += __shfl_xor(s, 16, 64);
  s += __shfl_xor(s, 32, 64);

  float lse = m + __logf(s);  // per-sample; identical across q-groups
  lse += __shfl_xor(lse, 1, 64);
  lse += __shfl_xor(lse, 2, 64);
  lse += __shfl_xor(lse, 4, 64);
  lse += __shfl_xor(lse, 8, 64);
  if (lane == 0) ws[WS_PART + blockIdx.x * 4 + w] = lse;
}

// Final: sum per-wave partials, combine with kl from ws.
__global__ __launch_bounds__(256) void finalize_kernel(
    const float* __restrict__ ws, float* __restrict__ out) {
  __shared__ float sW[4];
  int tid = threadIdx.x;
  int lane = tid & 63, w = tid >> 6;

  float s = 0.0f;
  #pragma unroll
  for (int i = 0; i < NPART / 256; ++i)
    s += ws[WS_PART + i * 256 + tid];
  #pragma unroll
  for (int o = 1; o < 64; o <<= 1) s += __shfl_xor(s, o, 64);
  if (lane == 0) sW[w] = s;
  __syncthreads();
  if (tid == 0) out[0] = ws[WS_KL] - (sW[0] + sW[1] + sW[2] + sW[3]);
}

extern "C" void kernel_launch(void* const* d_in, const int* in_sizes, int n_in,
                              void* d_out, int out_size, void* d_ws, size_t ws_size,
                              hipStream_t stream) {
  const float* X           = (const float*)d_in[0];
  const float* u_noise     = (const float*)d_in[1];
  const float* phi_logits  = (const float*)d_in[2];
  const float* q_mu        = (const float*)d_in[3];
  const float* q_logvar    = (const float*)d_in[4];
  const float* pi_logits   = (const float*)d_in[5];
  const float* prior_p     = (const float*)d_in[6];
  float* out = (float*)d_out;
  float* ws  = (float*)d_ws;

  setup_frags<<<1, 256, 0, stream>>>(u_noise, phi_logits, q_mu, q_logvar,
                                     pi_logits, prior_p, out, ws);
  gmm_main<<<NBLOCKS, 256, 0, stream>>>(X, ws, out);
  finalize_kernel<<<1, 256, 0, stream>>>(ws, out);
}

// Round 7
// 137.394 us; speedup vs baseline: 1.2745x; 1.1986x over previous
//
#include <hip/hip_runtime.h>
#include <hip/hip_bf16.h>
#include <math.h>

#define N_SAMPLES 262144
#define DDIM 64
#define KDIM 64
#define NBLOCKS 2048          // 2048 blocks x 8 waves x 16 rows
                              // (one tile per wave — frozen law: multi-tile
                              // waves inflate WRITE 2.3x, R2/R5; NT stores
                              // inflate WRITE 1.8x, R6)
#define NPART NBLOCKS         // one partial per block (LDS-reduced)

#define LOG2PI 1.8378770664093453f
#define PRIOR_LV0 -2.0f
#define IV0 7.389056098930650f  /* exp(2.0) */

// ws layout (floats):
//   [0, 4096)        : Bsw — 16 KB bf16 MFMA coef fragments
//                      frag-set s = kc*4+tile; lane l: 8 bf16 =
//                      B[kc*32 + (l>>4)*8 + j][tile*16 + (l&15)], j=0..7
//                      B[r][k] = r<64 ? P'[k][d=r] : Q[k][d=r-64]
//                      (same bits serve as the A-operand of the swapped
//                       mfma: A[m=cluster][k=d] fragment)
//   [4096, 4160)     : c[k]            (lp bias)
//   [4160, 4224)     : c[k] + logpi[k] (LSE bias, fused)
//   [4224, 4224+NPART): per-block LSE partials (plain stores)
//   [WS_KL]          : kl_phi * N  (written by setup)

#define WS_C      4096
#define WS_CL     4160
#define WS_PART   4224
#define WS_KL     (WS_PART + NPART)

typedef __attribute__((ext_vector_type(8))) short short8;
typedef __attribute__((ext_vector_type(4))) float floatx4;

static __device__ inline unsigned short f2bf_bits(float f) {
  union { float f; unsigned u; } v; v.f = f;
  unsigned r = v.u + 0x7fffu + ((v.u >> 16) & 1u);  // RNE
  return (unsigned short)(r >> 16);
}

__global__ __launch_bounds__(256) void setup_frags(
    const float* __restrict__ u_noise, const float* __restrict__ phi_logits,
    const float* __restrict__ q_mu, const float* __restrict__ q_logvar,
    const float* __restrict__ pi_logits, const float* __restrict__ prior_p,
    float* __restrict__ out, float* __restrict__ ws) {
  __shared__ float sPhi[DDIM];
  __shared__ float sR[DDIM];
  __shared__ float sLpi[KDIM];
  __shared__ float sBeta;
  __shared__ float sPart[4][KDIM];
  int tid = threadIdx.x;

  if (tid < 64) {  // exactly wave 0
    int d = tid;
    float u = u_noise[d];
    float g = -__logf(-__logf(u + 1e-9f) + 1e-9f);
    float phi = 1.0f / (1.0f + __expf(-(phi_logits[d] + g)));  // TEMP=1
    sPhi[d] = phi;
    sR[d] = -0.5f * (1.0f - phi) * IV0;

    float betap = -0.5f * (1.0f - phi) * (LOG2PI + PRIOR_LV0);
    #pragma unroll
    for (int o = 1; o < 64; o <<= 1) betap += __shfl_xor(betap, o, 64);
    if (d == 0) sBeta = betap;

    // log(softmax(pi_logits) + 1e-9)
    float l = pi_logits[d];
    float m = l;
    #pragma unroll
    for (int o = 1; o < 64; o <<= 1) m = fmaxf(m, __shfl_xor(m, o, 64));
    float e = __expf(l - m);
    float s = e;
    #pragma unroll
    for (int o = 1; o < 64; o <<= 1) s += __shfl_xor(s, o, 64);
    sLpi[d] = __logf(e / s + 1e-9f);
  } else if (tid >= 64 && tid < 128) {  // wave 1: q_phi + kl_phi
    int d = tid - 64;
    float qp = 1.0f / (1.0f + __expf(-phi_logits[d]));
    qp = fminf(fmaxf(qp, 1e-6f), 1.0f - 1e-6f);
    out[1 + d] = qp;
    float pp = fminf(fmaxf(prior_p[d], 1e-6f), 1.0f - 1e-6f);
    float klp = qp * (__logf(qp) - __logf(pp)) +
                (1.0f - qp) * (__logf(1.0f - qp) - __logf(1.0f - pp));
    #pragma unroll
    for (int o = 1; o < 64; o <<= 1) klp += __shfl_xor(klp, o, 64);
    if (d == 0) ws[WS_KL] = klp * (float)N_SAMPLES;
  }
  __syncthreads();

  // c_k partials (256 threads: k = tid&63, d-segment = tid>>6)
  {
    int k = tid & 63, seg = tid >> 6;
    const float* lvp = q_logvar + k * DDIM + seg * 16;
    const float* mup = q_mu + k * DDIM + seg * 16;
    float ap = 0.0f;
    #pragma unroll
    for (int dd = 0; dd < 16; ++dd) {
      int d = seg * 16 + dd;
      float lv = fminf(fmaxf(lvp[dd], -5.0f), 5.0f);
      float mu = mup[dd];
      ap += sPhi[d] * (LOG2PI + lv) + mu * mu * sPhi[d] * __expf(-lv);
    }
    sPart[seg][k] = ap;
  }

  // B-fragments built directly from params
  unsigned short* bsw = (unsigned short*)ws;
  #pragma unroll
  for (int p = 0; p < 4; ++p) {
    int pr = p * 256 + tid;      // 0..1023 = frag-set*64 + lane
    int s = pr >> 6, l = pr & 63;
    int kc = s >> 2, tl = s & 3, q = l >> 4, nn = l & 15;
    int k = tl * 16 + nn;
    int dbase = (kc & 1) * 32 + q * 8;
    const float* lvp = q_logvar + k * DDIM + dbase;
    float4 lv0 = *(const float4*)lvp;
    float4 lv1 = *(const float4*)(lvp + 4);
    float lvv[8] = {lv0.x, lv0.y, lv0.z, lv0.w, lv1.x, lv1.y, lv1.z, lv1.w};
    short r8[8];
    if (kc < 2) {  // P' rows
      #pragma unroll
      for (int j = 0; j < 8; ++j) {
        int d = dbase + j;
        float lv = fminf(fmaxf(lvv[j], -5.0f), 5.0f);
        r8[j] = (short)f2bf_bits(-0.5f * sPhi[d] * __expf(-lv) + sR[d]);
      }
    } else {       // Q rows
      const float* mup = q_mu + k * DDIM + dbase;
      float4 mu0 = *(const float4*)mup;
      float4 mu1 = *(const float4*)(mup + 4);
      float muv[8] = {mu0.x, mu0.y, mu0.z, mu0.w, mu1.x, mu1.y, mu1.z, mu1.w};
      #pragma unroll
      for (int j = 0; j < 8; ++j) {
        int d = dbase + j;
        float lv = fminf(fmaxf(lvv[j], -5.0f), 5.0f);
        r8[j] = (short)f2bf_bits(muv[j] * sPhi[d] * __expf(-lv));
      }
    }
    ((short8*)bsw)[pr] = (short8){r8[0], r8[1], r8[2], r8[3],
                                  r8[4], r8[5], r8[6], r8[7]};
  }

  __syncthreads();
  if (tid < 64) {
    float alpha = sPart[0][tid] + sPart[1][tid] + sPart[2][tid] + sPart[3][tid];
    float c = -0.5f * alpha + sBeta;  // c_k
    ws[WS_C + tid] = c;
    ws[WS_CL + tid] = c + sLpi[tid];  // c_k + log pi_k
  }
}

// Main kernel: 2048 blocks x 8 waves, ONE 16-row tile per wave (R4's
// per-wave behavior exactly — cached stores, single store burst, then
// done). 512-thread blocks halve block-start count and staging traffic;
// 4 blocks/CU x 8 waves = 32 waves/CU. Per-block LDS reduction of the
// 8 wave partials -> one ws write per block.
__global__ __launch_bounds__(512, 8) void gmm_main(
    const float* __restrict__ X, float* __restrict__ ws,
    float* __restrict__ out) {
  __shared__ short8 sB[1024];     // 16 KB: 16 frag-sets x 64 lanes
  __shared__ float sCB[KDIM];     // c_k
  __shared__ float sCL[KDIM];     // c_k + log pi_k
  __shared__ float sW[8];
  int tid  = threadIdx.x;
  int lane = tid & 63;
  int w    = tid >> 6;  // 0..7
  int n    = lane & 15;   // sample within tile == C/D column
  int q    = lane >> 4;   // quad: C/D rows (clusters) q*4..q*4+3
  long rbase = ((long)blockIdx.x * 8 + w) * 16;

  // ---- X loads issued first (independent of LDS staging; hide HBM latency)
  const float* xr = X + (rbase + n) * DDIM + q * 8;
  float4 xa0 = *(const float4*)(xr);
  float4 xa1 = *(const float4*)(xr + 4);
  float4 xb0 = *(const float4*)(xr + 32);
  float4 xb1 = *(const float4*)(xr + 36);

  // ---- stage B frags + bias tables into LDS (once per block, 512 thr)
  {
    const short8* Bf = (const short8*)ws;
    sB[tid]       = Bf[tid];
    sB[512 + tid] = Bf[512 + tid];
    if (tid < KDIM) { sCB[tid] = ws[WS_C + tid]; sCL[tid] = ws[WS_CL + tid]; }
  }
  __syncthreads();

  // ---- X fragments: kc0 = x^2 lo, kc1 = x^2 hi, kc2 = x lo, kc3 = x hi
  short8 a[4];
  {
    float xa[8] = {xa0.x, xa0.y, xa0.z, xa0.w, xa1.x, xa1.y, xa1.z, xa1.w};
    float xb[8] = {xb0.x, xb0.y, xb0.z, xb0.w, xb1.x, xb1.y, xb1.z, xb1.w};
    #pragma unroll
    for (int j = 0; j < 8; ++j) {
      a[0][j] = (short)f2bf_bits(xa[j] * xa[j]);
      a[1][j] = (short)f2bf_bits(xb[j] * xb[j]);
      a[2][j] = (short)f2bf_bits(xa[j]);
      a[3][j] = (short)f2bf_bits(xb[j]);
    }
  }

  // ---- MFMA: coef frags (LDS) as A, X frags as B -> D[cluster][sample]
  floatx4 acc[4];
  #pragma unroll
  for (int t = 0; t < 4; ++t) acc[t] = (floatx4){0.f, 0.f, 0.f, 0.f};
  #pragma unroll
  for (int kc = 0; kc < 4; ++kc) {
    #pragma unroll
    for (int t = 0; t < 4; ++t) {
      short8 b = sB[(kc * 4 + t) * 64 + lane];
      acc[t] = __builtin_amdgcn_mfma_f32_16x16x32_bf16(b, a[kc], acc[t], 0, 0, 0);
    }
  }

  // ---- epilogue: bias + 16B cached store per tile-col + lane-local LSE
  float* lp = out + 1 + DDIM;           // float-offset 65
  long rowoff = (rbase + n) * KDIM;
  #pragma unroll
  for (int t = 0; t < 4; ++t) {
    float4 cb = *(const float4*)&sCB[t * 16 + q * 4];
    float4 cl = *(const float4*)&sCL[t * 16 + q * 4];
    float o4[4];
    o4[0] = acc[t][0] + cb.x;
    o4[1] = acc[t][1] + cb.y;
    o4[2] = acc[t][2] + cb.z;
    o4[3] = acc[t][3] + cb.w;
    // 16B store at 4B alignment; MUST stay cached (L2 merges the
    // sector-straddling stores — NT doubled WRITE_SIZE in R6)
    __builtin_memcpy(lp + rowoff + t * 16 + q * 4, o4, 16);
    acc[t][0] += cl.x;
    acc[t][1] += cl.y;
    acc[t][2] += cl.z;
    acc[t][3] += cl.w;
  }

  float m = acc[0][0];
  #pragma unroll
  for (int t = 0; t < 4; ++t)
    #pragma unroll
    for (int r = 0; r < 4; ++r) m = fmaxf(m, acc[t][r]);
  m = fmaxf(m, __shfl_xor(m, 16, 64));
  m = fmaxf(m, __shfl_xor(m, 32, 64));

  float s = 0.0f;
  #pragma unroll
  for (int t = 0; t < 4; ++t)
    #pragma unroll
    for (int r = 0; r < 4; ++r) s += __expf(acc[t][r] - m);
  s += __shfl_xor(s, 16, 64);
  s += __shfl_xor(s, 32, 64);

  float lse = m + __logf(s);  // per-sample; identical across q-groups
  lse += __shfl_xor(lse, 1, 64);
  lse += __shfl_xor(lse, 2, 64);
  lse += __shfl_xor(lse, 4, 64);
  lse += __shfl_xor(lse, 8, 64);
  if (lane == 0) sW[w] = lse;
  __syncthreads();
  if (tid == 0) {
    ws[WS_PART + blockIdx.x] = sW[0] + sW[1] + sW[2] + sW[3] +
                               sW[4] + sW[5] + sW[6] + sW[7];
  }
}

// Final: sum per-block partials, combine with kl from ws.
__global__ __launch_bounds__(256) void finalize_kernel(
    const float* __restrict__ ws, float* __restrict__ out) {
  __shared__ float sW[4];
  int tid = threadIdx.x;
  int lane = tid & 63, w = tid >> 6;

  float s = 0.0f;
  #pragma unroll
  for (int i = 0; i < NPART / 256; ++i)
    s += ws[WS_PART + i * 256 + tid];
  #pragma unroll
  for (int o = 1; o < 64; o <<= 1) s += __shfl_xor(s, o, 64);
  if (lane == 0) sW[w] = s;
  __syncthreads();
  if (tid == 0) out[0] = ws[WS_KL] - (sW[0] + sW[1] + sW[2] + sW[3]);
}

extern "C" void kernel_launch(void* const* d_in, const int* in_sizes, int n_in,
                              void* d_out, int out_size, void* d_ws, size_t ws_size,
                              hipStream_t stream) {
  const float* X           = (const float*)d_in[0];
  const float* u_noise     = (const float*)d_in[1];
  const float* phi_logits  = (const float*)d_in[2];
  const float* q_mu        = (const float*)d_in[3];
  const float* q_logvar    = (const float*)d_in[4];
  const float* pi_logits   = (const float*)d_in[5];
  const float* prior_p     = (const float*)d_in[6];
  float* out = (float*)d_out;
  float* ws  = (float*)d_ws;

  setup_frags<<<1, 256, 0, stream>>>(u_noise, phi_logits, q_mu, q_logvar,
                                     pi_logits, prior_p, out, ws);
  gmm_main<<<NBLOCKS, 512, 0, stream>>>(X, ws, out);
  finalize_kernel<<<1, 256, 0, stream>>>(ws, out);
}

// Round 8
// 136.246 us; speedup vs baseline: 1.2853x; 1.0084x over previous
//
#include <hip/hip_runtime.h>
#include <hip/hip_bf16.h>
#include <math.h>

#define N_SAMPLES 262144
#define DDIM 64
#define KDIM 64
#define NBLOCKS 2048          // 2048 blocks x 8 waves x 16 rows
                              // (one tile per wave — frozen law: multi-tile
                              // waves inflate WRITE 2.3x, R2/R5; NT stores
                              // inflate WRITE 1.8x, R6)
#define NPART NBLOCKS         // one partial per block (LDS-reduced)

#define LOG2PI 1.8378770664093453f
#define PRIOR_LV0 -2.0f
#define IV0 7.389056098930650f  /* exp(2.0) */

// ws layout (floats):
//   [0, 4096)        : Bsw — 16 KB bf16 MFMA coef fragments
//   [4096, 4160)     : c[k]      (lp bias)
//   [4160, 4224)     : logpi[k]  (LSE bias; lp already contains c)
//   [4224, 4224+NPART): per-block LSE partials
//   [WS_KL]          : kl_phi * N  (written by setup)

#define WS_C      4096
#define WS_CL     4160
#define WS_PART   4224
#define WS_KL     (WS_PART + NPART)

typedef __attribute__((ext_vector_type(8))) short short8;
typedef __attribute__((ext_vector_type(4))) float floatx4;

static __device__ inline unsigned short f2bf_bits(float f) {
  union { float f; unsigned u; } v; v.f = f;
  unsigned r = v.u + 0x7fffu + ((v.u >> 16) & 1u);  // RNE
  return (unsigned short)(r >> 16);
}

__global__ __launch_bounds__(256) void setup_frags(
    const float* __restrict__ u_noise, const float* __restrict__ phi_logits,
    const float* __restrict__ q_mu, const float* __restrict__ q_logvar,
    const float* __restrict__ pi_logits, const float* __restrict__ prior_p,
    float* __restrict__ out, float* __restrict__ ws) {
  __shared__ float sPhi[DDIM];
  __shared__ float sR[DDIM];
  __shared__ float sLpi[KDIM];
  __shared__ float sBeta;
  __shared__ float sPart[4][KDIM];
  int tid = threadIdx.x;

  if (tid < 64) {  // exactly wave 0
    int d = tid;
    float u = u_noise[d];
    float g = -__logf(-__logf(u + 1e-9f) + 1e-9f);
    float phi = 1.0f / (1.0f + __expf(-(phi_logits[d] + g)));  // TEMP=1
    sPhi[d] = phi;
    sR[d] = -0.5f * (1.0f - phi) * IV0;

    float betap = -0.5f * (1.0f - phi) * (LOG2PI + PRIOR_LV0);
    #pragma unroll
    for (int o = 1; o < 64; o <<= 1) betap += __shfl_xor(betap, o, 64);
    if (d == 0) sBeta = betap;

    // log(softmax(pi_logits) + 1e-9)
    float l = pi_logits[d];
    float m = l;
    #pragma unroll
    for (int o = 1; o < 64; o <<= 1) m = fmaxf(m, __shfl_xor(m, o, 64));
    float e = __expf(l - m);
    float s = e;
    #pragma unroll
    for (int o = 1; o < 64; o <<= 1) s += __shfl_xor(s, o, 64);
    sLpi[d] = __logf(e / s + 1e-9f);
  } else if (tid >= 64 && tid < 128) {  // wave 1: q_phi + kl_phi
    int d = tid - 64;
    float qp = 1.0f / (1.0f + __expf(-phi_logits[d]));
    qp = fminf(fmaxf(qp, 1e-6f), 1.0f - 1e-6f);
    out[1 + d] = qp;
    float pp = fminf(fmaxf(prior_p[d], 1e-6f), 1.0f - 1e-6f);
    float klp = qp * (__logf(qp) - __logf(pp)) +
                (1.0f - qp) * (__logf(1.0f - qp) - __logf(1.0f - pp));
    #pragma unroll
    for (int o = 1; o < 64; o <<= 1) klp += __shfl_xor(klp, o, 64);
    if (d == 0) ws[WS_KL] = klp * (float)N_SAMPLES;
  }
  __syncthreads();

  // c_k partials (256 threads: k = tid&63, d-segment = tid>>6)
  {
    int k = tid & 63, seg = tid >> 6;
    const float* lvp = q_logvar + k * DDIM + seg * 16;
    const float* mup = q_mu + k * DDIM + seg * 16;
    float ap = 0.0f;
    #pragma unroll
    for (int dd = 0; dd < 16; ++dd) {
      int d = seg * 16 + dd;
      float lv = fminf(fmaxf(lvp[dd], -5.0f), 5.0f);
      float mu = mup[dd];
      ap += sPhi[d] * (LOG2PI + lv) + mu * mu * sPhi[d] * __expf(-lv);
    }
    sPart[seg][k] = ap;
  }

  // B-fragments built directly from params
  unsigned short* bsw = (unsigned short*)ws;
  #pragma unroll
  for (int p = 0; p < 4; ++p) {
    int pr = p * 256 + tid;      // 0..1023 = frag-set*64 + lane
    int s = pr >> 6, l = pr & 63;
    int kc = s >> 2, tl = s & 3, q = l >> 4, nn = l & 15;
    int k = tl * 16 + nn;
    int dbase = (kc & 1) * 32 + q * 8;
    const float* lvp = q_logvar + k * DDIM + dbase;
    float4 lv0 = *(const float4*)lvp;
    float4 lv1 = *(const float4*)(lvp + 4);
    float lvv[8] = {lv0.x, lv0.y, lv0.z, lv0.w, lv1.x, lv1.y, lv1.z, lv1.w};
    short r8[8];
    if (kc < 2) {  // P' rows
      #pragma unroll
      for (int j = 0; j < 8; ++j) {
        int d = dbase + j;
        float lv = fminf(fmaxf(lvv[j], -5.0f), 5.0f);
        r8[j] = (short)f2bf_bits(-0.5f * sPhi[d] * __expf(-lv) + sR[d]);
      }
    } else {       // Q rows
      const float* mup = q_mu + k * DDIM + dbase;
      float4 mu0 = *(const float4*)mup;
      float4 mu1 = *(const float4*)(mup + 4);
      float muv[8] = {mu0.x, mu0.y, mu0.z, mu0.w, mu1.x, mu1.y, mu1.z, mu1.w};
      #pragma unroll
      for (int j = 0; j < 8; ++j) {
        int d = dbase + j;
        float lv = fminf(fmaxf(lvv[j], -5.0f), 5.0f);
        r8[j] = (short)f2bf_bits(muv[j] * sPhi[d] * __expf(-lv));
      }
    }
    ((short8*)bsw)[pr] = (short8){r8[0], r8[1], r8[2], r8[3],
                                  r8[4], r8[5], r8[6], r8[7]};
  }

  __syncthreads();
  if (tid < 64) {
    float alpha = sPart[0][tid] + sPart[1][tid] + sPart[2][tid] + sPart[3][tid];
    float c = -0.5f * alpha + sBeta;  // c_k
    ws[WS_C + tid] = c;
    ws[WS_CL + tid] = sLpi[tid];  // raw log pi_k (lp bias already in c)
  }
}

// Main kernel: 2048 blocks x 8 waves, ONE 16-row tile per wave, B table
// staged in LDS (R4/R7 structure). R8 delta: ALIGNED lp stores — each
// lane stores the 16B-aligned window k=16t+4q+3..+6 built from its own
// o[t][3] plus o[.][0..2] rotated from lane+16 (12 shuffles); q=0 lanes
// add the row head (k=0..2), q=3 lanes the row tail (k=63). Same bytes,
// zero sector-straddling store transactions.
__global__ __launch_bounds__(512, 8) void gmm_main(
    const float* __restrict__ X, float* __restrict__ ws,
    float* __restrict__ out) {
  __shared__ short8 sB[1024];     // 16 KB: 16 frag-sets x 64 lanes
  __shared__ float sCB[KDIM];     // c_k
  __shared__ float sLP[KDIM];     // log pi_k
  __shared__ float sW[8];
  int tid  = threadIdx.x;
  int lane = tid & 63;
  int w    = tid >> 6;  // 0..7
  int n    = lane & 15;   // sample within tile == C/D column
  int q    = lane >> 4;   // quad: C/D rows (clusters) q*4..q*4+3
  long rbase = ((long)blockIdx.x * 8 + w) * 16;

  // ---- X loads issued first (independent of LDS staging; hide HBM latency)
  const float* xr = X + (rbase + n) * DDIM + q * 8;
  float4 xa0 = *(const float4*)(xr);
  float4 xa1 = *(const float4*)(xr + 4);
  float4 xb0 = *(const float4*)(xr + 32);
  float4 xb1 = *(const float4*)(xr + 36);

  // ---- stage B frags + bias tables into LDS (once per block, 512 thr)
  {
    const short8* Bf = (const short8*)ws;
    sB[tid]       = Bf[tid];
    sB[512 + tid] = Bf[512 + tid];
    if (tid < KDIM) { sCB[tid] = ws[WS_C + tid]; sLP[tid] = ws[WS_CL + tid]; }
  }
  __syncthreads();

  // ---- X fragments: kc0 = x^2 lo, kc1 = x^2 hi, kc2 = x lo, kc3 = x hi
  short8 a[4];
  {
    float xa[8] = {xa0.x, xa0.y, xa0.z, xa0.w, xa1.x, xa1.y, xa1.z, xa1.w};
    float xb[8] = {xb0.x, xb0.y, xb0.z, xb0.w, xb1.x, xb1.y, xb1.z, xb1.w};
    #pragma unroll
    for (int j = 0; j < 8; ++j) {
      a[0][j] = (short)f2bf_bits(xa[j] * xa[j]);
      a[1][j] = (short)f2bf_bits(xb[j] * xb[j]);
      a[2][j] = (short)f2bf_bits(xa[j]);
      a[3][j] = (short)f2bf_bits(xb[j]);
    }
  }

  // ---- MFMA: coef frags (LDS) as A, X frags as B -> D[cluster][sample]
  floatx4 acc[4];
  #pragma unroll
  for (int t = 0; t < 4; ++t) acc[t] = (floatx4){0.f, 0.f, 0.f, 0.f};
  #pragma unroll
  for (int kc = 0; kc < 4; ++kc) {
    #pragma unroll
    for (int t = 0; t < 4; ++t) {
      short8 b = sB[(kc * 4 + t) * 64 + lane];
      acc[t] = __builtin_amdgcn_mfma_f32_16x16x32_bf16(b, a[kc], acc[t], 0, 0, 0);
    }
  }

  // ---- bias into o[t] (lane k = t*16+q*4+r), in place
  #pragma unroll
  for (int t = 0; t < 4; ++t) {
    float4 cb = *(const float4*)&sCB[t * 16 + q * 4];
    acc[t][0] += cb.x;
    acc[t][1] += cb.y;
    acc[t][2] += cb.z;
    acc[t][3] += cb.w;
  }

  // ---- aligned store epilogue
  float* lp = out + 1 + DDIM;           // float-offset 65
  long rowoff = (rbase + n) * KDIM;
  int src = (lane + 16) & 63;           // lane of quad q+1 (mod 4), same n

  // head: k=0..2 (q=0 lanes): dword @+0 (4B), float2 @+1 (8B-aligned)
  if (q == 0) {
    lp[rowoff] = acc[0][0];
    float2 h2 = {acc[0][1], acc[0][2]};
    *(float2*)(lp + rowoff + 1) = h2;
  }
  // tail: k=63 (q=3 lanes): dword, 16B-aligned
  if (q == 3) {
    lp[rowoff + 63] = acc[3][3];
  }
  // 16B-aligned chunks k=16t+4q+3..+6 (chunk t=3,q=3 excluded)
  #pragma unroll
  for (int t = 0; t < 4; ++t) {
    // source-side select: lane q==0 provides o[t+1][j] (its receiver is q=3)
    float s0 = (q == 0 && t < 3) ? acc[t + 1][0] : acc[t][0];
    float s1 = (q == 0 && t < 3) ? acc[t + 1][1] : acc[t][1];
    float s2 = (q == 0 && t < 3) ? acc[t + 1][2] : acc[t][2];
    float r0 = __shfl(s0, src, 64);
    float r1 = __shfl(s1, src, 64);
    float r2 = __shfl(s2, src, 64);
    if (!(q == 3 && t == 3)) {
      float4 o4 = {acc[t][3], r0, r1, r2};
      *(float4*)(lp + rowoff + t * 16 + q * 4 + 3) = o4;  // byte%16==0
    }
  }

  // ---- lane-local LSE over v = o + log pi
  #pragma unroll
  for (int t = 0; t < 4; ++t) {
    float4 lp4 = *(const float4*)&sLP[t * 16 + q * 4];
    acc[t][0] += lp4.x;
    acc[t][1] += lp4.y;
    acc[t][2] += lp4.z;
    acc[t][3] += lp4.w;
  }

  float m = acc[0][0];
  #pragma unroll
  for (int t = 0; t < 4; ++t)
    #pragma unroll
    for (int r = 0; r < 4; ++r) m = fmaxf(m, acc[t][r]);
  m = fmaxf(m, __shfl_xor(m, 16, 64));
  m = fmaxf(m, __shfl_xor(m, 32, 64));

  float s = 0.0f;
  #pragma unroll
  for (int t = 0; t < 4; ++t)
    #pragma unroll
    for (int r = 0; r < 4; ++r) s += __expf(acc[t][r] - m);
  s += __shfl_xor(s, 16, 64);
  s += __shfl_xor(s, 32, 64);

  float lse = m + __logf(s);  // per-sample; identical across q-groups
  lse += __shfl_xor(lse, 1, 64);
  lse += __shfl_xor(lse, 2, 64);
  lse += __shfl_xor(lse, 4, 64);
  lse += __shfl_xor(lse, 8, 64);
  if (lane == 0) sW[w] = lse;
  __syncthreads();
  if (tid == 0) {
    ws[WS_PART + blockIdx.x] = sW[0] + sW[1] + sW[2] + sW[3] +
                               sW[4] + sW[5] + sW[6] + sW[7];
  }
}

// Final: sum per-block partials, combine with kl from ws.
__global__ __launch_bounds__(256) void finalize_kernel(
    const float* __restrict__ ws, float* __restrict__ out) {
  __shared__ float sW[4];
  int tid = threadIdx.x;
  int lane = tid & 63, w = tid >> 6;

  float s = 0.0f;
  #pragma unroll
  for (int i = 0; i < NPART / 256; ++i)
    s += ws[WS_PART + i * 256 + tid];
  #pragma unroll
  for (int o = 1; o < 64; o <<= 1) s += __shfl_xor(s, o, 64);
  if (lane == 0) sW[w] = s;
  __syncthreads();
  if (tid == 0) out[0] = ws[WS_KL] - (sW[0] + sW[1] + sW[2] + sW[3]);
}

extern "C" void kernel_launch(void* const* d_in, const int* in_sizes, int n_in,
                              void* d_out, int out_size, void* d_ws, size_t ws_size,
                              hipStream_t stream) {
  const float* X           = (const float*)d_in[0];
  const float* u_noise     = (const float*)d_in[1];
  const float* phi_logits  = (const float*)d_in[2];
  const float* q_mu        = (const float*)d_in[3];
  const float* q_logvar    = (const float*)d_in[4];
  const float* pi_logits   = (const float*)d_in[5];
  const float* prior_p     = (const float*)d_in[6];
  float* out = (float*)d_out;
  float* ws  = (float*)d_ws;

  setup_frags<<<1, 256, 0, stream>>>(u_noise, phi_logits, q_mu, q_logvar,
                                     pi_logits, prior_p, out, ws);
  gmm_main<<<NBLOCKS, 512, 0, stream>>>(X, ws, out);
  finalize_kernel<<<1, 256, 0, stream>>>(ws, out);
}